// Round 11
// baseline (259.241 us; speedup 1.0000x reference)
//
#include <hip/hip_runtime.h>

#define DIM 64
#define GPW 4    // 16-row groups per wave in gemm
#define BSHIFT 9
#define BSPAN 512      // nodes per bucket
#define MAXNB 512      // max buckets (N <= 262144; here N=200000 -> NB=391)
#define CNTB 256       // CSR blocks in bucket_count / scatter

typedef __attribute__((ext_vector_type(8))) __bf16 bf16x8;
typedef __attribute__((ext_vector_type(8))) unsigned short u16x8;
typedef __attribute__((ext_vector_type(4))) unsigned u32x4;
typedef __attribute__((ext_vector_type(4))) float f32x4;

__device__ __forceinline__ f32x4 mfma16(bf16x8 a, bf16x8 b, f32x4 c) {
    return __builtin_amdgcn_mfma_f32_16x16x32_bf16(a, b, c, 0, 0, 0);
}

__device__ __forceinline__ float bf2f(unsigned short u) {
    return __uint_as_float((unsigned)u << 16);
}

// ---------- gemm body (device function, packed into count kernel) ----------

// h = x @ W (UNSCALED). fp32 two-tensor input path.
__device__ __forceinline__ void gemm_f32_body(
    int bid, const float* __restrict__ xa_, const float* __restrict__ xb_,
    int split, const float* __restrict__ W, __bf16* __restrict__ h,
    int n, int ngroups) {
    int lane = threadIdx.x & 63;
    int q = lane >> 4, t = lane & 15;
    int wv = __builtin_amdgcn_readfirstlane((threadIdx.x >> 6) & 3);
    int g0 = (bid * 4 + wv) * GPW;
    if (g0 >= ngroups) return;

    bf16x8 Bf[4][2];
#pragma unroll
    for (int nt = 0; nt < 4; ++nt)
#pragma unroll
        for (int kt = 0; kt < 2; ++kt) {
            bf16x8 f;
#pragma unroll
            for (int j = 0; j < 8; ++j)
                f[j] = (__bf16)W[(kt * 32 + q * 8 + j) * DIM + nt * 16 + t];
            Bf[nt][kt] = f;
        }

    auto loadA = [&](int r0, f32x4* raw) {
        int row = r0 + t;
        if (row >= n) row = n - 1;
        const float* xr = (row < split)
            ? (xa_ + (size_t)row * DIM)
            : (xb_ + (size_t)(row - split) * DIM);
        raw[0] = *(const f32x4*)(xr + q * 8);
        raw[1] = *(const f32x4*)(xr + q * 8 + 4);
        raw[2] = *(const f32x4*)(xr + 32 + q * 8);
        raw[3] = *(const f32x4*)(xr + 32 + q * 8 + 4);
    };

    f32x4 cur[4];
    loadA(g0 * 16, cur);

#pragma unroll 1
    for (int gi = 0; gi < GPW; ++gi) {
        int g = g0 + gi;
        if (g >= ngroups) break;
        int r0 = g * 16;
        f32x4 nxt[4];
        bool pf = (gi + 1 < GPW) && (g + 1 < ngroups);
        if (pf) loadA(r0 + 16, nxt);

        bf16x8 A0, A1;
#pragma unroll
        for (int j = 0; j < 4; ++j) {
            A0[j] = (__bf16)cur[0][j]; A0[j + 4] = (__bf16)cur[1][j];
            A1[j] = (__bf16)cur[2][j]; A1[j + 4] = (__bf16)cur[3][j];
        }

        f32x4 z = {0.f, 0.f, 0.f, 0.f};
        f32x4 acc[4];
#pragma unroll
        for (int nt = 0; nt < 4; ++nt)
            acc[nt] = mfma16(A1, Bf[nt][1], mfma16(A0, Bf[nt][0], z));

#pragma unroll
        for (int nt = 0; nt < 4; ++nt)
#pragma unroll
            for (int reg = 0; reg < 4; ++reg) {
                int row = r0 + q * 4 + reg;
                if (row < n)
                    h[(size_t)row * DIM + nt * 16 + t] = (__bf16)acc[nt][reg];
            }
#pragma unroll
        for (int i = 0; i < 4; ++i) cur[i] = nxt[i];
    }
}

// ---------- CSR build ----------

// P1 packed: blocks [0,CNTB) bucket-count; blocks [CNTB,...) gemm1 (x@W1,
// unscaled — CSR-independent, overlaps the chain).
__global__ __launch_bounds__(256) void count_gemm_kernel(
    const int* __restrict__ ei, int* __restrict__ bpart, int E_,
    const float* __restrict__ ua, const float* __restrict__ ub, int split,
    const float* __restrict__ W1, __bf16* __restrict__ h, int n, int ngroups) {
    if (blockIdx.x >= CNTB) {
        gemm_f32_body(blockIdx.x - CNTB, ua, ub, split, W1, h, n, ngroups);
        return;
    }
    __shared__ int hist[MAXNB];
    int tid = threadIdx.x;
    int bid = blockIdx.x;
    hist[tid] = 0; hist[tid + 256] = 0;
    __syncthreads();
    int chunk = (E_ + CNTB - 1) / CNTB;
    int e0 = bid * chunk, e1 = min(E_, e0 + chunk);
    for (int e = e0 + tid; e < e1; e += 256)
        atomicAdd(&hist[ei[E_ + e] >> BSHIFT], 1);
    __syncthreads();
    bpart[bid * MAXNB + tid] = hist[tid];
    bpart[bid * MAXNB + tid + 256] = hist[tid + 256];
}

// P2: 1 block reduces the CNTBx512 partials and exclusive-scans -> bptr, bcur.
__global__ __launch_bounds__(512) void bucket_scan_kernel(
    const int* __restrict__ bpart, int* __restrict__ bptr,
    int* __restrict__ bcur, int* __restrict__ rowptr,
    int nblk, int N_, int E_) {
    __shared__ int sm[512];
    int tid = threadIdx.x;
    int tot = 0;
#pragma unroll 8
    for (int blk = 0; blk < nblk; ++blk)
        tot += bpart[blk * MAXNB + tid];
    sm[tid] = tot;
    __syncthreads();
    for (int off = 1; off < 512; off <<= 1) {
        int t = 0;
        if (tid >= off) t = sm[tid - off];
        __syncthreads();
        if (tid >= off) sm[tid] += t;
        __syncthreads();
    }
    int ex = sm[tid] - tot;
    bptr[tid] = ex;
    bcur[tid] = ex;
    if (tid == 0) { bptr[MAXNB] = E_; rowptr[N_] = E_; }
}

// P3: coarse scatter into bucket-contiguous spans.
__global__ __launch_bounds__(512) void scatter_kernel(
    const int* __restrict__ ei, int* __restrict__ bcur,
    unsigned* __restrict__ packed, int E_, int nblk) {
    __shared__ int h[MAXNB];
    int tid = threadIdx.x;
    int chunk = (E_ + nblk - 1) / nblk;
    int e0 = blockIdx.x * chunk, e1 = min(E_, e0 + chunk);
    h[tid] = 0;
    __syncthreads();
    for (int e = e0 + tid; e < e1; e += 512)
        atomicAdd(&h[ei[E_ + e] >> BSHIFT], 1);
    __syncthreads();
    int c = h[tid];
    h[tid] = c ? atomicAdd(&bcur[tid], c) : 0;
    __syncthreads();
    for (int e = e0 + tid; e < e1; e += 512) {
        int s = ei[e], d = ei[E_ + e];
        int b = d >> BSHIFT;
        int pos = atomicAdd(&h[b], 1);
        packed[pos] = ((unsigned)s << BSHIFT) | (unsigned)(d & (BSPAN - 1));
    }
}

// P4: per-bucket fine sort. Emits rowptr + dinv.
__global__ __launch_bounds__(256) void bucket_sort_kernel(
    const unsigned* __restrict__ packed, const int* __restrict__ bptr,
    int* __restrict__ rowptr, int* __restrict__ srcs,
    float* __restrict__ dinv, int N_) {
    __shared__ int cnt[BSPAN];
    __shared__ int sc[256];
    int tid = threadIdx.x;
    int b = blockIdx.x;
    int beg = bptr[b], end = bptr[b + 1];
    int node0 = b << BSHIFT;
    int nn = min(BSPAN, N_ - node0);
    cnt[tid] = 0; cnt[tid + 256] = 0;
    __syncthreads();
    for (int i = beg + tid; i < end; i += 256)
        atomicAdd(&cnt[packed[i] & (BSPAN - 1)], 1);
    __syncthreads();
    int degA = cnt[tid], degB = cnt[tid + 256];
    int a0 = cnt[2 * tid], a1 = cnt[2 * tid + 1];
    if (tid < nn) dinv[node0 + tid] = rsqrtf((float)(1 + degA));
    if (tid + 256 < nn) dinv[node0 + tid + 256] = rsqrtf((float)(1 + degB));
    int tot = a0 + a1;
    sc[tid] = tot;
    __syncthreads();
    for (int off = 1; off < 256; off <<= 1) {
        int t = 0;
        if (tid >= off) t = sc[tid - off];
        __syncthreads();
        if (tid >= off) sc[tid] += t;
        __syncthreads();
    }
    int ex = sc[tid] - tot;
    cnt[2 * tid] = ex;
    cnt[2 * tid + 1] = ex + a0;
    __syncthreads();
    if (tid < nn) rowptr[node0 + tid] = beg + cnt[tid];
    if (tid + 256 < nn) rowptr[node0 + tid + 256] = beg + cnt[tid + 256];
    __syncthreads();
    for (int i = beg + tid; i < end; i += 256) {
        unsigned p = packed[i];
        int pos = atomicAdd(&cnt[p & (BSPAN - 1)], 1);
        srcs[beg + pos] = (int)(p >> BSHIFT);
    }
}

// ---------- layer kernels ----------

// agg1: t1[n] = bf16(b1 + dinv[n] * Sum_{s in {n} U N(n)} dinv[s]*h[s]).
// 8 nodes/wave (R4-verified); gathered rows are unscaled x@W1.
__global__ __launch_bounds__(256) void agg1_kernel(
    const int* __restrict__ rowptr, const int* __restrict__ srcs,
    const __bf16* __restrict__ h, const float* __restrict__ bias,
    const float* __restrict__ dinv, __bf16* __restrict__ out, int n) {
    int lane = threadIdx.x & 63;
    int t8 = lane & 7;
    int wv = threadIdx.x >> 6;
    int node = (blockIdx.x * 4 + wv) * 8 + (lane >> 3);
    bool alive = node < n;
    int nd = alive ? node : (n - 1);
    int beg = rowptr[nd], end = rowptr[nd + 1];
    float dn = dinv[nd];

    u16x8 sv = *(const u16x8*)(h + (size_t)nd * DIM + t8 * 8);
    float acc[8];
#pragma unroll
    for (int j = 0; j < 8; ++j) acc[j] = bf2f(sv[j]) * dn;

    int i = beg;
    while (i < end) {
        int idx = i + t8;
        int sl = (idx < end) ? srcs[idx] : 0;
        float dsl = (idx < end) ? dinv[sl] : 0.f;
        u16x8 vv[8];
#pragma unroll
        for (int k = 0; k < 8; ++k) {
            int s = __shfl(sl, (lane & 56) | k);
            vv[k] = *(const u16x8*)(h + (size_t)s * DIM + t8 * 8);
        }
#pragma unroll
        for (int k = 0; k < 8; ++k)
            if (i + k < end) {
                float w = __shfl(dsl, (lane & 56) | k);
#pragma unroll
                for (int j = 0; j < 8; ++j)
                    acc[j] = fmaf(bf2f(vv[k][j]), w, acc[j]);
            }
        i += 8;
    }

    f32x4 b0 = *(const f32x4*)(bias + t8 * 8);
    f32x4 b1 = *(const f32x4*)(bias + t8 * 8 + 4);
    if (alive) {
        bf16x8 o;
#pragma unroll
        for (int j = 0; j < 4; ++j) {
            o[j]     = (__bf16)fmaf(dn, acc[j],     b0[j]);
            o[j + 4] = (__bf16)fmaf(dn, acc[j + 4], b1[j]);
        }
        *(bf16x8*)(out + (size_t)node * DIM + t8 * 8) = o;
    }
}

// agg2+gemm2 fused via linearity:
//   out[n] = b2 + (dinv[n] * Sum_{s in {n} U N(n)} dinv[s]*t1[s]) @ W2
// Gather t1 (same pattern/volume as gathering h2 would be), then per-wave
// MFMA tail on the 8 AGGREGATED rows: bf16-round, 8-shfl permute into the
// A-frag layout (rows 8-15 duplicate, masked at store), 8 MFMAs with W2
// frags, +b2, fp32 store. Deletes gemm2's 51.2 MB round trip + launch.
__global__ __launch_bounds__(256) void agg_gemm2_kernel(
    const int* __restrict__ rowptr, const int* __restrict__ srcs,
    const __bf16* __restrict__ t1, const float* __restrict__ W2,
    const float* __restrict__ b2, const float* __restrict__ dinv,
    float* __restrict__ out, int n) {
    int lane = threadIdx.x & 63;
    int t8 = lane & 7;
    int wv = __builtin_amdgcn_readfirstlane(threadIdx.x >> 6);
    int q = lane >> 4, t = lane & 15;
    int wbase = (blockIdx.x * 4 + wv) * 8;
    int node = wbase + (lane >> 3);
    int nd = (node < n) ? node : (n - 1);
    int beg = rowptr[nd], end = rowptr[nd + 1];
    float dn = dinv[nd];

    u16x8 sv = *(const u16x8*)(t1 + (size_t)nd * DIM + t8 * 8);
    float acc[8];
#pragma unroll
    for (int j = 0; j < 8; ++j) acc[j] = bf2f(sv[j]) * dn;

    int i = beg;
    while (i < end) {
        int idx = i + t8;
        int sl = (idx < end) ? srcs[idx] : 0;
        float dsl = (idx < end) ? dinv[sl] : 0.f;
        u16x8 vv[8];
#pragma unroll
        for (int k = 0; k < 8; ++k) {
            int s = __shfl(sl, (lane & 56) | k);
            vv[k] = *(const u16x8*)(t1 + (size_t)s * DIM + t8 * 8);
        }
#pragma unroll
        for (int k = 0; k < 8; ++k)
            if (i + k < end) {
                float w = __shfl(dsl, (lane & 56) | k);
#pragma unroll
                for (int j = 0; j < 8; ++j)
                    acc[j] = fmaf(bf2f(vv[k][j]), w, acc[j]);
            }
        i += 8;
    }

    // aggregated row, outer dinv[n] scale, bf16-round
    bf16x8 o;
#pragma unroll
    for (int j = 0; j < 8; ++j) o[j] = (__bf16)(dn * acc[j]);

    // ---- MFMA tail (wave-local) ----
    __builtin_amdgcn_sched_barrier(0);
    bf16x8 Bf[4][2];
#pragma unroll
    for (int nt = 0; nt < 4; ++nt)
#pragma unroll
        for (int kt = 0; kt < 2; ++kt) {
            bf16x8 f;
#pragma unroll
            for (int j = 0; j < 8; ++j)
                f[j] = (__bf16)W2[(kt * 32 + q * 8 + j) * DIM + nt * 16 + t];
            Bf[nt][kt] = f;
        }

    // permute rows into A-frag layout: lane(t,q) <- row (t&7), dims q*8..+7
    // (A0) and 32+q*8..+7 (A1): src lanes (t&7)*8+q and +4.
    u32x4 ov = __builtin_bit_cast(u32x4, o);
    int s0 = ((t & 7) << 3) | q;
    u32x4 a0v, a1v;
#pragma unroll
    for (int j = 0; j < 4; ++j) {
        a0v[j] = (unsigned)__shfl((int)ov[j], s0);
        a1v[j] = (unsigned)__shfl((int)ov[j], s0 + 4);
    }
    bf16x8 A0 = __builtin_bit_cast(bf16x8, a0v);
    bf16x8 A1 = __builtin_bit_cast(bf16x8, a1v);

    f32x4 z = {0.f, 0.f, 0.f, 0.f};
    f32x4 acc2[4];
#pragma unroll
    for (int nt = 0; nt < 4; ++nt)
        acc2[nt] = mfma16(A1, Bf[nt][1], mfma16(A0, Bf[nt][0], z));

    // D: row = q*4+reg (real rows 0-7 -> q<2), col = nt*16+t
    if (q < 2) {
#pragma unroll
        for (int nt = 0; nt < 4; ++nt) {
            float bv = b2[nt * 16 + t];
#pragma unroll
            for (int reg = 0; reg < 4; ++reg) {
                int row = wbase + q * 4 + reg;
                if (row < n)
                    out[(size_t)row * DIM + nt * 16 + t] = acc2[nt][reg] + bv;
            }
        }
    }
}

static inline size_t align16(size_t x) { return (x + 15) & ~(size_t)15; }

extern "C" void kernel_launch(void* const* d_in, const int* in_sizes, int n_in,
                              void* d_out, int out_size, void* d_ws, size_t ws_size,
                              hipStream_t stream) {
    const int* ei         = (const int*)d_in[0];
    const float* user_emb = (const float*)d_in[1];
    const float* item_emb = (const float*)d_in[2];
    const float* W1 = (const float*)d_in[3];
    const float* b1 = (const float*)d_in[4];
    const float* W2 = (const float*)d_in[5];
    const float* b2 = (const float*)d_in[6];
    float* out = (float*)d_out;

    const int E_ = in_sizes[0] / 2;
    const int NU = in_sizes[1] / DIM;
    const int NI = in_sizes[2] / DIM;
    const int N_ = NU + NI;
    const int NB = (N_ + BSPAN - 1) >> BSHIFT;   // 391

    // workspace layout (16B-aligned)
    char* p = (char*)d_ws;
    int* srcs   = (int*)p;               p += align16((size_t)E_ * 4);
    __bf16* h   = (__bf16*)p;            p += align16((size_t)N_ * DIM * 2);
    __bf16* t1  = (__bf16*)p;            p += align16((size_t)N_ * DIM * 2);
    float* dinv = (float*)p;             p += align16((size_t)N_ * 4);
    int* rowptr = (int*)p;               p += align16((size_t)(N_ + 1) * 4);
    int* bpart  = (int*)p;               p += align16((size_t)CNTB * MAXNB * 4);
    int* bptr   = (int*)p;               p += align16((size_t)(MAXNB + 1) * 4);
    int* bcur   = (int*)p;               p += align16((size_t)MAXNB * 4);
    // packed edge buffer aliases t1: fully consumed by bucket_sort before
    // agg1 writes t1.
    unsigned* packed = (unsigned*)t1;

    int NG = (N_ + 15) / 16;                       // 16-row groups
    int gblocks = (NG + 4 * GPW - 1) / (4 * GPW);  // 4 waves/block
    int ablocks = (N_ + 31) / 32;                  // 32 nodes/block (8/wave)

    // P1: bucket-count packed with gemm1 (x@W1 unscaled — CSR-independent)
    count_gemm_kernel<<<CNTB + gblocks, 256, 0, stream>>>(
        ei, bpart, E_, user_emb, item_emb, NU, W1, h, N_, NG);
    bucket_scan_kernel<<<1, 512, 0, stream>>>(bpart, bptr, bcur, rowptr,
                                              CNTB, N_, E_);
    scatter_kernel<<<CNTB, 512, 0, stream>>>(ei, bcur, packed, E_, CNTB);
    bucket_sort_kernel<<<NB, 256, 0, stream>>>(packed, bptr, rowptr, srcs, dinv, N_);

    // layer 1 aggregate
    agg1_kernel<<<ablocks, 256, 0, stream>>>(rowptr, srcs, h, b1, dinv, t1, N_);
    // layer 2 aggregate with fused W2 matmul tail
    agg_gemm2_kernel<<<ablocks, 256, 0, stream>>>(rowptr, srcs, t1, W2, b2,
                                                  dinv, out, N_);
}

// Round 12
// 246.803 us; speedup vs baseline: 1.0504x; 1.0504x over previous
//
#include <hip/hip_runtime.h>

#define DIM 64
#define GPW 4    // 16-row groups per wave in gemm
#define BSHIFT 9
#define BSPAN 512      // nodes per bucket
#define MAXNB 512      // max buckets (N <= 262144; here N=200000 -> NB=391)
#define CNTB 256       // CSR blocks in bucket_count / scatter

typedef __attribute__((ext_vector_type(8))) __bf16 bf16x8;
typedef __attribute__((ext_vector_type(8))) unsigned short u16x8;
typedef __attribute__((ext_vector_type(4))) float f32x4;

__device__ __forceinline__ f32x4 mfma16(bf16x8 a, bf16x8 b, f32x4 c) {
    return __builtin_amdgcn_mfma_f32_16x16x32_bf16(a, b, c, 0, 0, 0);
}

__device__ __forceinline__ float bf2f(unsigned short u) {
    return __uint_as_float((unsigned)u << 16);
}

// ---------- gemm1 body (device function, packed into CSR kernels) ----------
// h = x @ W1 (UNSCALED; dinv applied per-row in agg1). fp32 input.
// bid indexes 4-wave (256-thread) gemm units; callers with 512-thread
// blocks pass bid = 2*b + (threadIdx.x>>8). Units self-limit via
// g0 >= ngroups.
__device__ __forceinline__ void gemm_f32_body(
    int bid, const float* __restrict__ xa_, const float* __restrict__ xb_,
    int split, const float* __restrict__ W, __bf16* __restrict__ h,
    int n, int ngroups) {
    int lane = threadIdx.x & 63;
    int q = lane >> 4, t = lane & 15;
    int wv = __builtin_amdgcn_readfirstlane((threadIdx.x >> 6) & 3);
    int g0 = (bid * 4 + wv) * GPW;
    if (g0 >= ngroups) return;

    bf16x8 Bf[4][2];
#pragma unroll
    for (int nt = 0; nt < 4; ++nt)
#pragma unroll
        for (int kt = 0; kt < 2; ++kt) {
            bf16x8 f;
#pragma unroll
            for (int j = 0; j < 8; ++j)
                f[j] = (__bf16)W[(kt * 32 + q * 8 + j) * DIM + nt * 16 + t];
            Bf[nt][kt] = f;
        }

    auto loadA = [&](int r0, f32x4* raw) {
        int row = r0 + t;
        if (row >= n) row = n - 1;
        const float* xr = (row < split)
            ? (xa_ + (size_t)row * DIM)
            : (xb_ + (size_t)(row - split) * DIM);
        raw[0] = *(const f32x4*)(xr + q * 8);
        raw[1] = *(const f32x4*)(xr + q * 8 + 4);
        raw[2] = *(const f32x4*)(xr + 32 + q * 8);
        raw[3] = *(const f32x4*)(xr + 32 + q * 8 + 4);
    };

    f32x4 cur[4];
    loadA(g0 * 16, cur);

#pragma unroll 1
    for (int gi = 0; gi < GPW; ++gi) {
        int g = g0 + gi;
        if (g >= ngroups) break;
        int r0 = g * 16;
        f32x4 nxt[4];
        bool pf = (gi + 1 < GPW) && (g + 1 < ngroups);
        if (pf) loadA(r0 + 16, nxt);

        bf16x8 A0, A1;
#pragma unroll
        for (int j = 0; j < 4; ++j) {
            A0[j] = (__bf16)cur[0][j]; A0[j + 4] = (__bf16)cur[1][j];
            A1[j] = (__bf16)cur[2][j]; A1[j + 4] = (__bf16)cur[3][j];
        }

        f32x4 z = {0.f, 0.f, 0.f, 0.f};
        f32x4 acc[4];
#pragma unroll
        for (int nt = 0; nt < 4; ++nt)
            acc[nt] = mfma16(A1, Bf[nt][1], mfma16(A0, Bf[nt][0], z));

#pragma unroll
        for (int nt = 0; nt < 4; ++nt)
#pragma unroll
            for (int reg = 0; reg < 4; ++reg) {
                int row = r0 + q * 4 + reg;
                if (row < n)
                    h[(size_t)row * DIM + nt * 16 + t] = (__bf16)acc[nt][reg];
            }
#pragma unroll
        for (int i = 0; i < 4; ++i) cur[i] = nxt[i];
    }
}

// ---------- CSR build, each stage packed with a slice of gemm1 ----------

// P1: blocks [0,CNTB) bucket-count; blocks [CNTB,..) gemm1 units [0,GA).
__global__ __launch_bounds__(256) void count_gemm_kernel(
    const int* __restrict__ ei, int* __restrict__ bpart, int E_,
    const float* __restrict__ ua, const float* __restrict__ ub, int split,
    const float* __restrict__ W1, __bf16* __restrict__ h, int n, int ngroups) {
    if (blockIdx.x >= CNTB) {
        gemm_f32_body(blockIdx.x - CNTB, ua, ub, split, W1, h, n, ngroups);
        return;
    }
    __shared__ int hist[MAXNB];
    int tid = threadIdx.x;
    int bid = blockIdx.x;
    hist[tid] = 0; hist[tid + 256] = 0;
    __syncthreads();
    int chunk = (E_ + CNTB - 1) / CNTB;
    int e0 = bid * chunk, e1 = min(E_, e0 + chunk);
    for (int e = e0 + tid; e < e1; e += 256)
        atomicAdd(&hist[ei[E_ + e] >> BSHIFT], 1);
    __syncthreads();
    bpart[bid * MAXNB + tid] = hist[tid];
    bpart[bid * MAXNB + tid + 256] = hist[tid + 256];
}

// P2: 1 block reduces the CNTBx512 partials and exclusive-scans -> bptr, bcur.
__global__ __launch_bounds__(512) void bucket_scan_kernel(
    const int* __restrict__ bpart, int* __restrict__ bptr,
    int* __restrict__ bcur, int* __restrict__ rowptr,
    int nblk, int N_, int E_) {
    __shared__ int sm[512];
    int tid = threadIdx.x;
    int tot = 0;
#pragma unroll 8
    for (int blk = 0; blk < nblk; ++blk)
        tot += bpart[blk * MAXNB + tid];
    sm[tid] = tot;
    __syncthreads();
    for (int off = 1; off < 512; off <<= 1) {
        int t = 0;
        if (tid >= off) t = sm[tid - off];
        __syncthreads();
        if (tid >= off) sm[tid] += t;
        __syncthreads();
    }
    int ex = sm[tid] - tot;
    bptr[tid] = ex;
    bcur[tid] = ex;
    if (tid == 0) { bptr[MAXNB] = E_; rowptr[N_] = E_; }
}

// P3: blocks [0,CNTB) coarse-scatter; blocks [CNTB,..) carry TWO gemm1
// units each (512 threads): units goff + 2*(b-CNTB) + (tid>>8).
__global__ __launch_bounds__(512) void scatter_gemm_kernel(
    const int* __restrict__ ei, int* __restrict__ bcur,
    unsigned* __restrict__ packed, int E_,
    const float* __restrict__ ua, const float* __restrict__ ub, int split,
    const float* __restrict__ W1, __bf16* __restrict__ hout, int n,
    int ngroups, int goff) {
    if (blockIdx.x >= CNTB) {
        int bid = goff + (blockIdx.x - CNTB) * 2 + (threadIdx.x >> 8);
        gemm_f32_body(bid, ua, ub, split, W1, hout, n, ngroups);
        return;
    }
    __shared__ int h[MAXNB];
    int tid = threadIdx.x;
    int chunk = (E_ + CNTB - 1) / CNTB;
    int e0 = blockIdx.x * chunk, e1 = min(E_, e0 + chunk);
    h[tid] = 0;
    __syncthreads();
    for (int e = e0 + tid; e < e1; e += 512)
        atomicAdd(&h[ei[E_ + e] >> BSHIFT], 1);
    __syncthreads();
    int c = h[tid];
    h[tid] = c ? atomicAdd(&bcur[tid], c) : 0;
    __syncthreads();
    for (int e = e0 + tid; e < e1; e += 512) {
        int s = ei[e], d = ei[E_ + e];
        int b = d >> BSHIFT;
        int pos = atomicAdd(&h[b], 1);
        packed[pos] = ((unsigned)s << BSHIFT) | (unsigned)(d & (BSPAN - 1));
    }
}

// P4: blocks [0,NB) per-bucket fine sort; blocks [NB,..) gemm1 units
// [goff,..). Emits rowptr + dinv. agg1 launches after this dispatch, so
// all gemm1 slices complete before h is consumed.
__global__ __launch_bounds__(256) void sort_gemm_kernel(
    const unsigned* __restrict__ packed, const int* __restrict__ bptr,
    int* __restrict__ rowptr, int* __restrict__ srcs,
    float* __restrict__ dinv, int N_, int NB,
    const float* __restrict__ ua, const float* __restrict__ ub, int split,
    const float* __restrict__ W1, __bf16* __restrict__ hout, int n,
    int ngroups, int goff) {
    if (blockIdx.x >= NB) {
        gemm_f32_body(goff + ((int)blockIdx.x - NB), ua, ub, split, W1, hout,
                      n, ngroups);
        return;
    }
    __shared__ int cnt[BSPAN];
    __shared__ int sc[256];
    int tid = threadIdx.x;
    int b = blockIdx.x;
    int beg = bptr[b], end = bptr[b + 1];
    int node0 = b << BSHIFT;
    int nn = min(BSPAN, N_ - node0);
    cnt[tid] = 0; cnt[tid + 256] = 0;
    __syncthreads();
    for (int i = beg + tid; i < end; i += 256)
        atomicAdd(&cnt[packed[i] & (BSPAN - 1)], 1);
    __syncthreads();
    int degA = cnt[tid], degB = cnt[tid + 256];
    int a0 = cnt[2 * tid], a1 = cnt[2 * tid + 1];
    if (tid < nn) dinv[node0 + tid] = rsqrtf((float)(1 + degA));
    if (tid + 256 < nn) dinv[node0 + tid + 256] = rsqrtf((float)(1 + degB));
    int tot = a0 + a1;
    sc[tid] = tot;
    __syncthreads();
    for (int off = 1; off < 256; off <<= 1) {
        int t = 0;
        if (tid >= off) t = sc[tid - off];
        __syncthreads();
        if (tid >= off) sc[tid] += t;
        __syncthreads();
    }
    int ex = sc[tid] - tot;
    cnt[2 * tid] = ex;
    cnt[2 * tid + 1] = ex + a0;
    __syncthreads();
    if (tid < nn) rowptr[node0 + tid] = beg + cnt[tid];
    if (tid + 256 < nn) rowptr[node0 + tid + 256] = beg + cnt[tid + 256];
    __syncthreads();
    for (int i = beg + tid; i < end; i += 256) {
        unsigned p = packed[i];
        int pos = atomicAdd(&cnt[p & (BSPAN - 1)], 1);
        srcs[beg + pos] = (int)(p >> BSHIFT);
    }
}

// ---------- layer kernels (R10-verified) ----------

// Standalone gemm for layer 2: h2 = (t1 @ W2) * dinv[row], bf16 input.
__global__ __launch_bounds__(256) void gemm_bf16_kernel(
    const __bf16* __restrict__ x, const float* __restrict__ W,
    const float* __restrict__ dinv, __bf16* __restrict__ h, int n, int ngroups) {
    int lane = threadIdx.x & 63;
    int q = lane >> 4, t = lane & 15;
    int wv = __builtin_amdgcn_readfirstlane(threadIdx.x >> 6);
    int g0 = (blockIdx.x * 4 + wv) * GPW;
    if (g0 >= ngroups) return;

    bf16x8 Bf[4][2];
#pragma unroll
    for (int nt = 0; nt < 4; ++nt)
#pragma unroll
        for (int kt = 0; kt < 2; ++kt) {
            bf16x8 f;
#pragma unroll
            for (int j = 0; j < 8; ++j)
                f[j] = (__bf16)W[(kt * 32 + q * 8 + j) * DIM + nt * 16 + t];
            Bf[nt][kt] = f;
        }

    auto loadA = [&](int r0, f32x4* raw) {
        int row = r0 + t;
        if (row >= n) row = n - 1;
        const __bf16* xr = x + (size_t)row * DIM;
        raw[0] = *(const f32x4*)(xr + q * 8);
        raw[1] = *(const f32x4*)(xr + 32 + q * 8);
    };

    f32x4 cur[2];
    loadA(g0 * 16, cur);

#pragma unroll 1
    for (int gi = 0; gi < GPW; ++gi) {
        int g = g0 + gi;
        if (g >= ngroups) break;
        int r0 = g * 16;
        f32x4 nxt[2];
        bool pf = (gi + 1 < GPW) && (g + 1 < ngroups);
        if (pf) loadA(r0 + 16, nxt);

        bf16x8 A0 = __builtin_bit_cast(bf16x8, cur[0]);
        bf16x8 A1 = __builtin_bit_cast(bf16x8, cur[1]);

        f32x4 z = {0.f, 0.f, 0.f, 0.f};
        f32x4 acc[4];
#pragma unroll
        for (int nt = 0; nt < 4; ++nt)
            acc[nt] = mfma16(A1, Bf[nt][1], mfma16(A0, Bf[nt][0], z));

        f32x4 d4 = *(const f32x4*)(dinv + r0 + q * 4);
#pragma unroll
        for (int nt = 0; nt < 4; ++nt)
#pragma unroll
            for (int reg = 0; reg < 4; ++reg) {
                int row = r0 + q * 4 + reg;
                if (row < n)
                    h[(size_t)row * DIM + nt * 16 + t] =
                        (__bf16)(acc[nt][reg] * d4[reg]);
            }
        cur[0] = nxt[0]; cur[1] = nxt[1];
    }
}

// Aggregation, 8 nodes/wave (R4-verified structure).
// SRC_SCALE: gathered rows are UNSCALED (layer-1 path) -> multiply each
// gathered row by dinv[s] (and self by dinv[node]) during accumulation.
template <typename OutT, bool SRC_SCALE>
__global__ __launch_bounds__(256) void agg_kernel(
    const int* __restrict__ rowptr, const int* __restrict__ srcs,
    const __bf16* __restrict__ h, const float* __restrict__ bias,
    const float* __restrict__ dinv, OutT* __restrict__ out, int n) {
    int lane = threadIdx.x & 63;
    int t8 = lane & 7;
    int wv = threadIdx.x >> 6;
    int node = (blockIdx.x * 4 + wv) * 8 + (lane >> 3);
    bool alive = node < n;
    int nd = alive ? node : (n - 1);
    int beg = rowptr[nd], end = rowptr[nd + 1];
    float dn = dinv[nd];

    u16x8 sv = *(const u16x8*)(h + (size_t)nd * DIM + t8 * 8);
    float selfscale = SRC_SCALE ? dn : 1.f;
    float acc[8];
#pragma unroll
    for (int j = 0; j < 8; ++j) acc[j] = bf2f(sv[j]) * selfscale;

    int i = beg;
    while (i < end) {
        int idx = i + t8;
        int sl = (idx < end) ? srcs[idx] : 0;
        float dsl = 0.f;
        if (SRC_SCALE && idx < end) dsl = dinv[sl];
        u16x8 vv[8];
#pragma unroll
        for (int k = 0; k < 8; ++k) {
            int s = __shfl(sl, (lane & 56) | k);
            vv[k] = *(const u16x8*)(h + (size_t)s * DIM + t8 * 8);
        }
#pragma unroll
        for (int k = 0; k < 8; ++k)
            if (i + k < end) {
                float w = SRC_SCALE ? __shfl(dsl, (lane & 56) | k) : 1.f;
#pragma unroll
                for (int j = 0; j < 8; ++j)
                    acc[j] = SRC_SCALE ? fmaf(bf2f(vv[k][j]), w, acc[j])
                                       : (acc[j] + bf2f(vv[k][j]));
            }
        i += 8;
    }

    f32x4 b0 = *(const f32x4*)(bias + t8 * 8);
    f32x4 b1 = *(const f32x4*)(bias + t8 * 8 + 4);
    if (alive) {
        if constexpr (sizeof(OutT) == 4) {
            f32x4 o0, o1;
#pragma unroll
            for (int j = 0; j < 4; ++j) {
                o0[j] = fmaf(dn, acc[j],     b0[j]);
                o1[j] = fmaf(dn, acc[j + 4], b1[j]);
            }
            float* op = (float*)out + (size_t)node * DIM + t8 * 8;
            *(f32x4*)op = o0;
            *(f32x4*)(op + 4) = o1;
        } else {
            bf16x8 o;
#pragma unroll
            for (int j = 0; j < 4; ++j) {
                o[j]     = (__bf16)fmaf(dn, acc[j],     b0[j]);
                o[j + 4] = (__bf16)fmaf(dn, acc[j + 4], b1[j]);
            }
            *(bf16x8*)((__bf16*)out + (size_t)node * DIM + t8 * 8) = o;
        }
    }
}

static inline size_t align16(size_t x) { return (x + 15) & ~(size_t)15; }

extern "C" void kernel_launch(void* const* d_in, const int* in_sizes, int n_in,
                              void* d_out, int out_size, void* d_ws, size_t ws_size,
                              hipStream_t stream) {
    const int* ei         = (const int*)d_in[0];
    const float* user_emb = (const float*)d_in[1];
    const float* item_emb = (const float*)d_in[2];
    const float* W1 = (const float*)d_in[3];
    const float* b1 = (const float*)d_in[4];
    const float* W2 = (const float*)d_in[5];
    const float* b2 = (const float*)d_in[6];
    float* out = (float*)d_out;

    const int E_ = in_sizes[0] / 2;
    const int NU = in_sizes[1] / DIM;
    const int NI = in_sizes[2] / DIM;
    const int N_ = NU + NI;
    const int NB = (N_ + BSPAN - 1) >> BSHIFT;   // 391

    // workspace layout (16B-aligned)
    char* p = (char*)d_ws;
    int* srcs   = (int*)p;               p += align16((size_t)E_ * 4);
    __bf16* h   = (__bf16*)p;            p += align16((size_t)N_ * DIM * 2);
    __bf16* t1  = (__bf16*)p;            p += align16((size_t)N_ * DIM * 2);
    float* dinv = (float*)p;             p += align16((size_t)N_ * 4);
    int* rowptr = (int*)p;               p += align16((size_t)(N_ + 1) * 4);
    int* bpart  = (int*)p;               p += align16((size_t)CNTB * MAXNB * 4);
    int* bptr   = (int*)p;               p += align16((size_t)(MAXNB + 1) * 4);
    int* bcur   = (int*)p;               p += align16((size_t)MAXNB * 4);
    // packed edge buffer aliases t1: fully consumed by sort before
    // agg1 writes t1.
    unsigned* packed = (unsigned*)t1;

    int NG = (N_ + 15) / 16;                       // 16-row groups
    int gblocks = (NG + 4 * GPW - 1) / (4 * GPW);  // 4-wave gemm units (782)
    int ablocks = (N_ + 31) / 32;                  // 32 nodes/block (8/wave)

    // split gemm1's units across the three CSR stages
    int GC = gblocks / 3;                 // with sort
    int GB = (gblocks / 3) & ~1;          // with scatter (even: 2 per 512-thr blk)
    int GA = gblocks - GB - GC;           // with count

    count_gemm_kernel<<<CNTB + GA, 256, 0, stream>>>(
        ei, bpart, E_, user_emb, item_emb, NU, W1, h, N_, NG);
    bucket_scan_kernel<<<1, 512, 0, stream>>>(bpart, bptr, bcur, rowptr,
                                              CNTB, N_, E_);
    scatter_gemm_kernel<<<CNTB + GB / 2, 512, 0, stream>>>(
        ei, bcur, packed, E_, user_emb, item_emb, NU, W1, h, N_, NG, GA);
    sort_gemm_kernel<<<NB + GC, 256, 0, stream>>>(
        packed, bptr, rowptr, srcs, dinv, N_, NB,
        user_emb, item_emb, NU, W1, h, N_, NG, GA + GB);

    // layer 1 aggregate (applies dinv[s] per gathered row + dinv[node])
    agg_kernel<__bf16, true><<<ablocks, 256, 0, stream>>>(rowptr, srcs, h, b1,
                                                          dinv, t1, N_);
    // layer 2
    gemm_bf16_kernel<<<gblocks, 256, 0, stream>>>(t1, W2, dinv, h, N_, NG);
    agg_kernel<float, false><<<ablocks, 256, 0, stream>>>(rowptr, srcs, h, b2,
                                                          dinv, out, N_);
}